// Round 8
// baseline (12944.917 us; speedup 1.0000x reference)
//
#include <hip/hip_runtime.h>

// ============================================================================
// 2-layer LSTM (B=256, T=1024, H=512, in=1) + linear head. fp32 in/out.
//
// R12 (from R11 @9.66ms): move recurrence sync/data legs off the agent fabric
// onto XCD-local L2. Evidence: period invariant to compute (R5/R11), poll
// shape (R9/R10); only store-path RT removal helped (R7). Model: agent-scope
// RT ~2us under load; chain has 3-4 legs -> 9.4us period.
//  - bx&7 heuristic: chunk c's 32 L0 WGs on one XCD, 32 L1 WGs on another.
//    VERIFIED AT RUNTIME via s_getreg(HW_REG_XCC_ID) exchange; group-uniform
//    fast/fallback verdict per 32-WG group (fallback = R11 agent path).
//  - Fast L0: h-exchange via local ring (plain full-line stores -> L2) +
//    volatile flag lines; polls carry buffer_inv (L1-only) in the spin loop.
//    Agent tail for L1's benefit: p agent copy + pf flag DEFERRED one step
//    (certified by next step's barrier drain). No sc1 inv (L1-only inv
//    every RL=4 steps; sc1 would DISCARD dirty local lines).
//  - Fast L1: q local ring + local flags (agent q copy deleted - no reader);
//    agent qf fire-and-forget (progress-only, no drain needed). p import:
//    each WG agent-loads only ITS 4KB slice of p_s, republishes into local
//    L2 (pimp) + flag; peers read locally (traffic x1 not x32).
//  - Agent rings RING 16->8 (guard slack 7 steps; lag ~2-4) to fit local
//    rings in ws: total 30.2MB (< 31.1MB used before).
// Math bit-identical to R11 (absmax 6.1e-5 expected).
// Predicted: fast-path dur 4.5-6.5ms, FETCH <300MB, MfmaUtil 20-28;
// flat+FETCH-collapse => verdict failed; hang => local protocol bug.
// ============================================================================

typedef _Float16 f16;
typedef _Float16 f16x8 __attribute__((ext_vector_type(8)));
typedef float f32x4 __attribute__((ext_vector_type(4)));
typedef unsigned long long u64;

#define NB 256
#define NT_ 1024
#define NH 512
#define RING 8            // agent transport ring
#define RL 4              // local (L2) transport ring
#define SLOT (NB * NH)    // 131072 elems per agent ring slot

__device__ __forceinline__ float sigm(float x)  { return 1.0f / (1.0f + __expf(-x)); }
__device__ __forceinline__ float tanhx(float x) { return 2.0f / (1.0f + __expf(-2.0f * x)) - 1.0f; }

// ---- agent-scope primitives (verified R3..R11) ----
__device__ __forceinline__ void st8(unsigned short* p, u64 v) {
  __hip_atomic_store((u64*)p, v, __ATOMIC_RELAXED, __HIP_MEMORY_SCOPE_AGENT);
}
__device__ __forceinline__ void stf(unsigned* p, unsigned v) {
  __hip_atomic_store(p, v, __ATOMIC_RELAXED, __HIP_MEMORY_SCOPE_AGENT);
}
__device__ __forceinline__ unsigned ldf(const unsigned* p) {
  return __hip_atomic_load(p, __ATOMIC_RELAXED, __HIP_MEMORY_SCOPE_AGENT);
}
__device__ __forceinline__ u64 ldf64(const unsigned short* p) {
  return __hip_atomic_load((const u64*)p, __ATOMIC_RELAXED, __HIP_MEMORY_SCOPE_AGENT);
}
// agent poll (flags monotonic)
__device__ __forceinline__ unsigned pollr(const unsigned* a, unsigned thr) {
  unsigned v;
  for (;;) {
    v = ldf(a);
    if (!~__ballot(v >= thr)) break;
    __builtin_amdgcn_s_sleep(1);
  }
  asm volatile("" ::: "memory");
  return v;
}
// ---- local (L2) primitives: volatile + L1-inv-in-loop (progress guaranteed
// regardless of volatile's L1-bypass semantics) ----
__device__ __forceinline__ void stv32(unsigned* p, unsigned v) { *(volatile unsigned*)p = v; }
__device__ __forceinline__ void stv64(unsigned short* p, u64 v) { *(volatile u64*)p = v; }
__device__ __forceinline__ void pollv(const unsigned* a, unsigned thr) {
  for (;;) {
    unsigned v = *(volatile const unsigned*)a;
    if (!~__ballot(v >= thr)) break;
    __builtin_amdgcn_s_sleep(1);
    asm volatile("buffer_inv" ::: "memory");   // L1-only: next read hits L2
  }
  asm volatile("" ::: "memory");
}

// agent flag lines: one 128B line per [chunk][slice<32][replica<4]
__device__ __forceinline__ unsigned* PFL(unsigned* pf, int c, int j, int r) {
  return pf + (((c * 32 + j) * 4) + r) * 32;
}
__device__ __forceinline__ unsigned* QFL(unsigned* qf, int c, int j, int r) {
  return qf + (((c * 32 + j) * 4) + r) * 32;
}
// local flag lines: one 128B line per [kind<3][chunk][slice<32]
// kind 0 = L0 p-local, 1 = L1 q-local, 2 = pimp (imported p)
__device__ __forceinline__ unsigned* LFL(unsigned* lf, int kind, int c, int j) {
  return lf + (((kind * 4 + c) * 32) + j) * 32;
}

// ---------------------------------------------------------------------------
__global__ void prep_xT(const float* __restrict__ inp, float* __restrict__ xT) {
  int g = blockIdx.x * 256 + threadIdx.x;
  int t = g >> 8, b = g & 255;
  xT[t * NB + b] = inp[b * NT_ + t];
}

// ---------------------------------------------------------------------------
// fp32 -> fp16 weights, unified tiling (verified R11): 32 slices x
// [nh<2][jt<2][kt<16][lane<64][j<8]; slice = 32768 elems.
__global__ void prep_w(const float* __restrict__ Wh0,
                       const float* __restrict__ Wx1,
                       const float* __restrict__ Wh1,
                       f16* __restrict__ dst) {
  int g = blockIdx.x * 256 + threadIdx.x;   // 3 * 2^20 threads
  int mat = g >> 20;
  int r = g & 0xFFFFF;
  int j = r & 7, ln = (r >> 3) & 63, kt = (r >> 9) & 15;
  int cl = ln & 15, qd = ln >> 4;
  int k = kt * 32 + qd * 8 + j;
  int jt = (r >> 13) & 1, nh = (r >> 14) & 1, sl = (r >> 15) & 31;
  const float* W = (mat == 0) ? Wh0 : (mat == 1) ? Wx1 : Wh1;
  int gate = jt * 2 + (cl >> 3);
  int gcol = gate * 512 + sl * 16 + nh * 8 + (cl & 7);
  size_t di = (size_t)mat * 1048576 + (size_t)sl * 32768 +
              (((size_t)(nh * 2 + jt) * 16 + kt) * 64 + ln) * 8 + j;
  dst[di] = (f16)W[(size_t)k * 2048 + gcol];
}

// ---------------------------------------------------------------------------
__global__ void reduce_out(const float* __restrict__ part8,
                           const float* __restrict__ bfp,
                           float* __restrict__ out) {
  int g = blockIdx.x * 256 + threadIdx.x;   // 262144 = b*1024+t
  float v = bfp[0];
#pragma unroll
  for (int j = 0; j < 8; ++j) v += part8[(size_t)j * (NB * NT_) + g];
  out[g] = v;
}

// ---------------------------------------------------------------------------
// agent h layouts (slice-major): x[slot<8][c<4][sl<32][row<64][unit<16]
// local rings: [c<4][slot<4][sl<32][row<64][unit<16] (32768 elems per slot)
__global__ __launch_bounds__(256, 1) void lstm_main(
    const float* __restrict__ xT,       // [T][B]
    const f16*  __restrict__ wsl,       // tiled fp16 weights (6 MB)
    const float* __restrict__ wx0,      // [2048]
    const float* __restrict__ bias0,    // [2048]
    const float* __restrict__ bias1,    // [2048]
    const float* __restrict__ wf,       // [512]
    unsigned short* p_hi, unsigned short* p_lo,   // agent p ring
    unsigned short* q_hi, unsigned short* q_lo,   // agent q ring (fallback only)
    unsigned int* pf, unsigned int* qf,           // agent flag lines
    unsigned short* ploc_hi, unsigned short* ploc_lo,  // L0 local ring
    unsigned short* qloc_hi, unsigned short* qloc_lo,  // L1 local ring
    unsigned short* pimp_hi, unsigned short* pimp_lo,  // L1 imported p
    unsigned int* lf,                   // local flag lines
    unsigned int* xtab,                 // [2][4][32] placement table
    float* part8)                       // [8][B][T]
{
  extern __shared__ char smem[];
  const int tid = threadIdx.x;
  const int wv = tid >> 6, ln = tid & 63;
  const int qd = ln >> 4, cl = ln & 15;
  const int bx = blockIdx.x;
  const int r8 = bx & 7, idx = bx >> 3;
  const bool isL0 = !(r8 & 1);
  const int c = r8 >> 1;
  const int sl = idx;                   // 0..31 both layers
  const float LO = 1.0f / 1024.0f;
  const int u = cl & 7, g01 = cl >> 3;
  const bool hiH = (cl < 8);
  const int lr = wv * 16 + cl;          // chunk-local A row

  // ---- stage weight slice(s) into LDS (once) ----
  if (isL0) {
    const int4* s0 = (const int4*)wsl + (size_t)sl * 4096;           // 64 KB
    int4* d = (int4*)smem;
    for (int i = tid; i < 4096; i += 256) d[i] = s0[i];
  } else {
    const int4* s1 = (const int4*)wsl + 131072 + (size_t)sl * 4096;  // Wx1 64 KB
    const int4* s2 = (const int4*)wsl + 262144 + (size_t)sl * 4096;  // Wh1 64 KB
    int4* d = (int4*)smem;
    for (int i = tid; i < 4096; i += 256) { d[i] = s1[i]; d[4096 + i] = s2[i]; }
  }

  // ---- placement verdict: are all 32 WGs of my group on one XCD? ----
  unsigned myx;
  asm("s_getreg_b32 %0, hwreg(HW_REG_XCC_ID)" : "=s"(myx));
  unsigned* xgrp = xtab + (isL0 ? 0 : 128) + c * 32;
  if (tid == 0) stf(xgrp + sl, myx + 1);
  unsigned xv_ = pollr(xgrp + (ln & 31), 1);        // one-time
  bool fast = __all((int)(xv_ == (unsigned)__shfl((int)xv_, 0)));
  __syncthreads();

  if (isL0) {
    // ======== layer 0: p_s = LSTM(x_s, p_{s-1}) ========
    float w0a[2], w0b[2], b0a[2], b0b[2];
#pragma unroll
    for (int nh = 0; nh < 2; ++nh) {
      int base = sl * 16 + nh * 8 + u;
      w0a[nh] = wx0[g01 * 512 + base];
      b0a[nh] = bias0[g01 * 512 + base];
      w0b[nh] = wx0[(2 + g01) * 512 + base];
      b0b[nh] = bias0[(2 + g01) * 512 + base];
    }
    float cst[2][4] = {{0.f,0.f,0.f,0.f},{0.f,0.f,0.f,0.f}};
    const f16x8* wl = (const f16x8*)smem;
    f16* sh  = (f16*)(smem + 65536);     // [64][16] hi stage (2 KB)
    f16* slo = sh + 1024;                // [64][16] lo stage (2 KB)
    const unsigned* lpf = (const unsigned*)LFL(lf, 0, c, ln & 31);  // peers
    const unsigned* agq = QFL(qf, c, ln & 31, sl & 3);              // guard

    for (int s = 0; s < NT_; ++s) {
      const int inv_per = fast ? (RL - 1) : (RING - 1);
      if ((s & inv_per) == 0 && s) {
        __syncthreads();
        if (wv == 0) {
          if (fast) asm volatile("buffer_inv" ::: "memory");            // L1 only
          else      asm volatile("buffer_inv sc1\n\ts_waitcnt vmcnt(0)" ::: "memory");
        }
        __syncthreads();
      }
      const int slw8 = s & (RING - 1);
      float4 xv = *(const float4*)(xT + s * NB + c * 64 + wv * 16 + qd * 4);
      if (s) {
        // lanes<32: peers done s-1; lanes>=32: ring guard (L1 >= s-RING+1)
        unsigned thrG = (s >= RING) ? (unsigned)(s - RING + 1) : 0u;
        if (fast) {
          for (;;) {
            unsigned v = (ln < 32) ? *(volatile const unsigned*)lpf : ldf(agq);
            unsigned t = (ln < 32) ? (unsigned)s : thrG;
            if (!~__ballot(v >= t)) break;
            __builtin_amdgcn_s_sleep(1);
            asm volatile("buffer_inv" ::: "memory");
          }
          asm volatile("" ::: "memory");
        } else {
          const unsigned* pwa = (ln < 32) ? PFL(pf, c, ln, sl & 3) : agq;
          pollr(pwa, (ln < 32) ? (unsigned)s : thrG);
        }
      }
      // ---- A fragments (p_{s-1} hi/lo) ----
      const f16* ah; const f16* al;
      if (fast) {
        int slr = (s + RL - 1) & (RL - 1);
        size_t b0_ = (size_t)(c * RL + slr) * 32768 +
                     (qd >> 1) * 1024 + lr * 16 + (qd & 1) * 8;
        ah = (const f16*)ploc_hi + b0_;
        al = (const f16*)ploc_lo + b0_;
      } else {
        int slr8 = (s + RING - 1) & (RING - 1);
        size_t b0_ = (size_t)slr8 * SLOT + (size_t)c * 32768 +
                     (qd >> 1) * 1024 + lr * 16 + (qd & 1) * 8;
        ah = (const f16*)p_hi + b0_;
        al = (const f16*)p_lo + b0_;
      }
      f16x8 Ah[16], Al[16];
#pragma unroll
      for (int kt = 0; kt < 16; ++kt) {
        Ah[kt] = *(const f16x8*)(ah + kt * 2048);
        Al[kt] = *(const f16x8*)(al + kt * 2048);
      }
      f32x4 acc[4], accL[4];
#pragma unroll
      for (int t4 = 0; t4 < 4; ++t4) {
        acc[t4] = (f32x4){0.f,0.f,0.f,0.f};
        accL[t4] = (f32x4){0.f,0.f,0.f,0.f};
      }
#pragma unroll
      for (int kt = 0; kt < 16; ++kt) {
#pragma unroll
        for (int t4 = 0; t4 < 4; ++t4) {
          f16x8 bw = wl[(t4 * 16 + kt) * 64 + ln];
          acc[t4]  = __builtin_amdgcn_mfma_f32_16x16x32_f16(Ah[kt], bw, acc[t4], 0, 0, 0);
          accL[t4] = __builtin_amdgcn_mfma_f32_16x16x32_f16(Al[kt], bw, accL[t4], 0, 0, 0);
        }
      }
      // ---- epilogue -> LDS stage ----
#pragma unroll
      for (int e = 0; e < 4; ++e) {
        float xe = (e == 0) ? xv.x : (e == 1) ? xv.y : (e == 2) ? xv.z : xv.w;
        int r = wv * 16 + qd * 4 + e;
#pragma unroll
        for (int nh = 0; nh < 2; ++nh) {
          float v0 = acc[nh*2+0][e] + accL[nh*2+0][e] * LO + xe * w0a[nh] + b0a[nh];
          float v1 = acc[nh*2+1][e] + accL[nh*2+1][e] * LO + xe * w0b[nh] + b0b[nh];
          float w0 = __shfl_xor(v0, 8, 16);
          float w1 = __shfl_xor(v1, 8, 16);
          float gi = hiH ? v0 : w0;
          float gf = hiH ? w0 : v0;
          float gg = hiH ? v1 : w1;
          float go = hiH ? w1 : v1;
          float ii = sigm(gi), ff = sigm(gf), tg = tanhx(gg), oo = sigm(go);
          cst[nh][e] = ff * cst[nh][e] + ii * tg;
          float h = oo * tanhx(cst[nh][e]);
          int su = r * 16 + nh * 8 + u;
          if (hiH) {
            sh[su] = (f16)h;
          } else {
            f16 hh = (f16)h;
            slo[su] = (f16)((h - (float)hh) * 1024.0f);
          }
        }
      }
      __syncthreads();    // stage ready; drains prior-step agent tail stores
      if (fast) {
        // deferred agent pf for p_{s-1} (data drained by the barrier above)
        if (s && tid < 4) stf(PFL(pf, c, sl, tid), (unsigned)s);
        // local full-line stores -> ploc slot s&3
        {
          unsigned short* bh = ploc_hi + (size_t)(c * RL + (s & (RL - 1))) * 32768 + (size_t)sl * 1024;
          unsigned short* bl = ploc_lo + (size_t)(c * RL + (s & (RL - 1))) * 32768 + (size_t)sl * 1024;
#pragma unroll
          for (int i = tid; i < 512; i += 256) {
            int strm = i >> 8, pc = i & 255;
            const f16* src = (strm ? slo : sh) + pc * 4;
            stv64((strm ? bl : bh) + pc * 4, *(const u64*)src);
          }
        }
        asm volatile("s_waitcnt vmcnt(0)" ::: "memory");
        __syncthreads();
        if (tid == 0) stv32(LFL(lf, 0, c, sl), (unsigned)(s + 1));   // local flag
        // agent tail: p copy for L1 (ack'd by next step's barrier)
        {
          unsigned short* bh = p_hi + (size_t)slw8 * SLOT + (size_t)c * 32768 + (size_t)sl * 1024;
          unsigned short* bl = p_lo + (size_t)slw8 * SLOT + (size_t)c * 32768 + (size_t)sl * 1024;
#pragma unroll
          for (int i = tid; i < 512; i += 256) {
            int strm = i >> 8, pc = i & 255;
            const f16* src = (strm ? slo : sh) + pc * 4;
            st8((strm ? bl : bh) + pc * 4, *(const u64*)src);
          }
        }
      } else {
        // fallback (R11): agent coop store -> drain -> agent flag
        unsigned short* bh = p_hi + (size_t)slw8 * SLOT + (size_t)c * 32768 + (size_t)sl * 1024;
        unsigned short* bl = p_lo + (size_t)slw8 * SLOT + (size_t)c * 32768 + (size_t)sl * 1024;
#pragma unroll
        for (int i = tid; i < 512; i += 256) {
          int strm = i >> 8, pc = i & 255;
          const f16* src = (strm ? slo : sh) + pc * 4;
          st8((strm ? bl : bh) + pc * 4, *(const u64*)src);
        }
        __syncthreads();   // implicit vmcnt(0): stores drained
        if (tid < 4) stf(PFL(pf, c, sl, tid), (unsigned)(s + 1));
      }
    }
    if (fast) {   // final deferred flag
      asm volatile("s_waitcnt vmcnt(0)" ::: "memory");
      __syncthreads();
      if (tid < 4) stf(PFL(pf, c, sl, tid), (unsigned)NT_);
    }
  } else {
    // ======== layer 1: q_s = LSTM(p_s, q_{s-1}) ========
    float b1c0[2], b1c1[2], wfv[2];
#pragma unroll
    for (int nh = 0; nh < 2; ++nh) {
      int base = sl * 16 + nh * 8 + u;
      b1c0[nh] = bias1[g01 * 512 + base];
      b1c1[nh] = bias1[(2 + g01) * 512 + base];
      wfv[nh] = wf[base];
    }
    float cst[2][4] = {{0.f,0.f,0.f,0.f},{0.f,0.f,0.f,0.f}};
    const f16x8* wx_ = (const f16x8*)smem;
    const f16x8* wh_ = (const f16x8*)(smem + 65536);
    f16* sh  = (f16*)(smem + 131072);   // [64][16] hi stage (2 KB)
    f16* slo = sh + 1024;               // [64][16] lo stage (2 KB)
    const unsigned* lqf = (const unsigned*)LFL(lf, 1, c, ln & 31);
    const unsigned* lif = (const unsigned*)LFL(lf, 2, c, ln & 31);

    for (int s = 0; s < NT_; ++s) {
      const int inv_per = fast ? (RL - 1) : (RING - 1);
      if ((s & inv_per) == 0 && s) {
        __syncthreads();
        if (wv == 0) {
          if (fast) asm volatile("buffer_inv" ::: "memory");
          else      asm volatile("buffer_inv sc1\n\ts_waitcnt vmcnt(0)" ::: "memory");
        }
        __syncthreads();
      }
      const int slw8 = s & (RING - 1);
      const int slw4 = s & (RL - 1);

      if (fast) {
        if (s) pollv(lqf, (unsigned)s);                 // peers done s-1
        // ---- import own slice of p_s: agent -> local L2 ----
        pollr(PFL(pf, c, sl, ln & 3), (unsigned)(s + 1));
        {
          size_t so = (size_t)slw8 * SLOT + (size_t)c * 32768 + (size_t)sl * 1024 + tid * 4;
          size_t dof = (size_t)(c * RL + slw4) * 32768 + (size_t)sl * 1024 + tid * 4;
          u64 vh = ldf64(p_hi + so);
          u64 vl = ldf64(p_lo + so);
          stv64(pimp_hi + dof, vh);
          stv64(pimp_lo + dof, vl);
        }
        asm volatile("s_waitcnt vmcnt(0)" ::: "memory");
        __syncthreads();
        if (tid == 0) stv32(LFL(lf, 2, c, sl), (unsigned)(s + 1));
        // ---- q loads (local ring) ----
        size_t qb = (size_t)(c * RL + ((s + RL - 1) & (RL - 1))) * 32768 +
                    (qd >> 1) * 1024 + lr * 16 + (qd & 1) * 8;
        const f16* aqh = (const f16*)qloc_hi + qb;
        const f16* aql = (const f16*)qloc_lo + qb;
        f16x8 Aq[16][2];
#pragma unroll
        for (int kt = 0; kt < 16; ++kt) {
          Aq[kt][0] = *(const f16x8*)(aqh + kt * 2048);
          Aq[kt][1] = *(const f16x8*)(aql + kt * 2048);
        }
        f32x4 acc[4], accL[4];
#pragma unroll
        for (int t4 = 0; t4 < 4; ++t4) {
          acc[t4] = (f32x4){0.f,0.f,0.f,0.f};
          accL[t4] = (f32x4){0.f,0.f,0.f,0.f};
        }
        // phase 1: q_{s-1} @ Wh1
#pragma unroll
        for (int kt = 0; kt < 16; ++kt) {
#pragma unroll
          for (int t4 = 0; t4 < 4; ++t4) {
            f16x8 bw = wh_[(t4 * 16 + kt) * 64 + ln];
            acc[t4]  = __builtin_amdgcn_mfma_f32_16x16x32_f16(Aq[kt][0], bw, acc[t4], 0, 0, 0);
            accL[t4] = __builtin_amdgcn_mfma_f32_16x16x32_f16(Aq[kt][1], bw, accL[t4], 0, 0, 0);
          }
        }
        // all slices imported?
        pollv(lif, (unsigned)(s + 1));
        size_t pb = (size_t)(c * RL + slw4) * 32768 +
                    (qd >> 1) * 1024 + lr * 16 + (qd & 1) * 8;
        const f16* aph = (const f16*)pimp_hi + pb;
        const f16* apl = (const f16*)pimp_lo + pb;
        f16x8 Ap[16][2];
#pragma unroll
        for (int kt = 0; kt < 16; ++kt) {
          Ap[kt][0] = *(const f16x8*)(aph + kt * 2048);
          Ap[kt][1] = *(const f16x8*)(apl + kt * 2048);
        }
        // phase 2: p_s @ Wx1
#pragma unroll
        for (int kt = 0; kt < 16; ++kt) {
#pragma unroll
          for (int t4 = 0; t4 < 4; ++t4) {
            f16x8 bw = wx_[(t4 * 16 + kt) * 64 + ln];
            acc[t4]  = __builtin_amdgcn_mfma_f32_16x16x32_f16(Ap[kt][0], bw, acc[t4], 0, 0, 0);
            accL[t4] = __builtin_amdgcn_mfma_f32_16x16x32_f16(Ap[kt][1], bw, accL[t4], 0, 0, 0);
          }
        }
        // ---- epilogue -> stage ----
        float po[4];
#pragma unroll
        for (int e = 0; e < 4; ++e) {
          po[e] = 0.0f;
#pragma unroll
          for (int nh = 0; nh < 2; ++nh) {
            float v0 = acc[nh*2+0][e] + accL[nh*2+0][e] * LO + b1c0[nh];
            float v1 = acc[nh*2+1][e] + accL[nh*2+1][e] * LO + b1c1[nh];
            float w0 = __shfl_xor(v0, 8, 16);
            float w1 = __shfl_xor(v1, 8, 16);
            float gi = hiH ? v0 : w0;
            float gf = hiH ? w0 : v0;
            float gg = hiH ? v1 : w1;
            float go = hiH ? w1 : v1;
            float ii = sigm(gi), ff = sigm(gf), tg = tanhx(gg), oo = sigm(go);
            cst[nh][e] = ff * cst[nh][e] + ii * tg;
            float h = oo * tanhx(cst[nh][e]);
            int su = (wv * 16 + qd * 4 + e) * 16 + nh * 8 + u;
            if (hiH) {
              sh[su] = (f16)h;
            } else {
              f16 hh = (f16)h;
              slo[su] = (f16)((h - (float)hh) * 1024.0f);
            }
            po[e] += hiH ? wfv[nh] * h : 0.0f;
          }
        }
        __syncthreads();
        // local q stores (full-line)
        {
          unsigned short* bh = qloc_hi + (size_t)(c * RL + slw4) * 32768 + (size_t)sl * 1024;
          unsigned short* bl = qloc_lo + (size_t)(c * RL + slw4) * 32768 + (size_t)sl * 1024;
#pragma unroll
          for (int i = tid; i < 512; i += 256) {
            int strm = i >> 8, pc = i & 255;
            const f16* src = (strm ? slo : sh) + pc * 4;
            stv64((strm ? bl : bh) + pc * 4, *(const u64*)src);
          }
        }
        asm volatile("s_waitcnt vmcnt(0)" ::: "memory");
        __syncthreads();
        if (tid == 0) stv32(LFL(lf, 1, c, sl), (unsigned)(s + 1));   // local qf
        if (tid < 4) stf(QFL(qf, c, sl, tid), (unsigned)(s + 1));    // guard (progress-only)
        // deferred head output
#pragma unroll
        for (int e = 0; e < 4; ++e) {
          float r = po[e];
#pragma unroll
          for (int m = 1; m < 16; m <<= 1) r += __shfl_xor(r, m, 16);
          if (cl == 0)
            atomicAdd(part8 + (size_t)(sl & 7) * (NB * NT_) +
                          (size_t)(c * 64 + wv * 16 + qd * 4 + e) * NT_ + s, r);
        }
      } else {
        // ================= fallback: R11 agent path (RING=8) =================
        bool early = false;
        if (s) {
          const unsigned* a_init = (ln < 32) ? QFL(qf, c, ln, sl & 3)
                                             : PFL(pf, c, ln - 32, sl & 3);
          unsigned thr_i = (ln < 32) ? (unsigned)s : (unsigned)(s + 1);
          unsigned v = ldf(a_init);
          u64 bal = __ballot(v >= thr_i);
          while ((unsigned)bal != 0xFFFFFFFFu) {
            __builtin_amdgcn_s_sleep(1);
            v = ldf(a_init);
            bal = __ballot(v >= thr_i);
          }
          asm volatile("" ::: "memory");
          early = ((unsigned)(bal >> 32) == 0xFFFFFFFFu);
        }
        size_t qb = (size_t)((s + RING - 1) & (RING - 1)) * SLOT + (size_t)c * 32768 +
                    (qd >> 1) * 1024 + lr * 16 + (qd & 1) * 8;
        const f16* aqh = (const f16*)q_hi + qb;
        const f16* aql = (const f16*)q_lo + qb;
        f16x8 Aq[16][2];
#pragma unroll
        for (int kt = 0; kt < 16; ++kt) {
          Aq[kt][0] = *(const f16x8*)(aqh + kt * 2048);
          Aq[kt][1] = *(const f16x8*)(aql + kt * 2048);
        }
        size_t pb = (size_t)slw8 * SLOT + (size_t)c * 32768 +
                    (qd >> 1) * 1024 + lr * 16 + (qd & 1) * 8;
        const f16* aph = (const f16*)p_hi + pb;
        const f16* apl = (const f16*)p_lo + pb;
        f16x8 Ap[16][2];
        if (early) {
#pragma unroll
          for (int kt = 0; kt < 16; ++kt) {
            Ap[kt][0] = *(const f16x8*)(aph + kt * 2048);
            Ap[kt][1] = *(const f16x8*)(apl + kt * 2048);
          }
        }
        f32x4 acc[4], accL[4];
#pragma unroll
        for (int t4 = 0; t4 < 4; ++t4) {
          acc[t4] = (f32x4){0.f,0.f,0.f,0.f};
          accL[t4] = (f32x4){0.f,0.f,0.f,0.f};
        }
#pragma unroll
        for (int kt = 0; kt < 16; ++kt) {
#pragma unroll
          for (int t4 = 0; t4 < 4; ++t4) {
            f16x8 bw = wh_[(t4 * 16 + kt) * 64 + ln];
            acc[t4]  = __builtin_amdgcn_mfma_f32_16x16x32_f16(Aq[kt][0], bw, acc[t4], 0, 0, 0);
            accL[t4] = __builtin_amdgcn_mfma_f32_16x16x32_f16(Aq[kt][1], bw, accL[t4], 0, 0, 0);
          }
        }
        if (!early) {
          pollr(PFL(pf, c, ln & 31, (sl + (ln >> 5)) & 3), (unsigned)(s + 1));
#pragma unroll
          for (int kt = 0; kt < 16; ++kt) {
            Ap[kt][0] = *(const f16x8*)(aph + kt * 2048);
            Ap[kt][1] = *(const f16x8*)(apl + kt * 2048);
          }
        }
#pragma unroll
        for (int kt = 0; kt < 16; ++kt) {
#pragma unroll
          for (int t4 = 0; t4 < 4; ++t4) {
            f16x8 bw = wx_[(t4 * 16 + kt) * 64 + ln];
            acc[t4]  = __builtin_amdgcn_mfma_f32_16x16x32_f16(Ap[kt][0], bw, acc[t4], 0, 0, 0);
            accL[t4] = __builtin_amdgcn_mfma_f32_16x16x32_f16(Ap[kt][1], bw, accL[t4], 0, 0, 0);
          }
        }
        float po[4];
#pragma unroll
        for (int e = 0; e < 4; ++e) {
          po[e] = 0.0f;
#pragma unroll
          for (int nh = 0; nh < 2; ++nh) {
            float v0 = acc[nh*2+0][e] + accL[nh*2+0][e] * LO + b1c0[nh];
            float v1 = acc[nh*2+1][e] + accL[nh*2+1][e] * LO + b1c1[nh];
            float w0 = __shfl_xor(v0, 8, 16);
            float w1 = __shfl_xor(v1, 8, 16);
            float gi = hiH ? v0 : w0;
            float gf = hiH ? w0 : v0;
            float gg = hiH ? v1 : w1;
            float go = hiH ? w1 : v1;
            float ii = sigm(gi), ff = sigm(gf), tg = tanhx(gg), oo = sigm(go);
            cst[nh][e] = ff * cst[nh][e] + ii * tg;
            float h = oo * tanhx(cst[nh][e]);
            int su = (wv * 16 + qd * 4 + e) * 16 + nh * 8 + u;
            if (hiH) {
              sh[su] = (f16)h;
            } else {
              f16 hh = (f16)h;
              slo[su] = (f16)((h - (float)hh) * 1024.0f);
            }
            po[e] += hiH ? wfv[nh] * h : 0.0f;
          }
        }
        __syncthreads();
        {
          unsigned short* bhq = q_hi + (size_t)slw8 * SLOT + (size_t)c * 32768 + (size_t)sl * 1024;
          unsigned short* blq = q_lo + (size_t)slw8 * SLOT + (size_t)c * 32768 + (size_t)sl * 1024;
#pragma unroll
          for (int i = tid; i < 512; i += 256) {
            int strm = i >> 8, pc = i & 255;
            const f16* src = (strm ? slo : sh) + pc * 4;
            st8((strm ? blq : bhq) + pc * 4, *(const u64*)src);
          }
        }
        __syncthreads();
        if (tid < 4) stf(QFL(qf, c, sl, tid), (unsigned)(s + 1));
#pragma unroll
        for (int e = 0; e < 4; ++e) {
          float r = po[e];
#pragma unroll
          for (int m = 1; m < 16; m <<= 1) r += __shfl_xor(r, m, 16);
          if (cl == 0)
            atomicAdd(part8 + (size_t)(sl & 7) * (NB * NT_) +
                          (size_t)(c * 64 + wv * 16 + qd * 4 + e) * NT_ + s, r);
        }
      }
    }
  }
}

// ---------------------------------------------------------------------------
extern "C" void kernel_launch(void* const* d_in, const int* in_sizes, int n_in,
                              void* d_out, int out_size, void* d_ws, size_t ws_size,
                              hipStream_t stream) {
  (void)in_sizes; (void)n_in; (void)out_size; (void)ws_size;
  const float* inp = (const float*)d_in[0];
  const float* Wx0 = (const float*)d_in[1];
  const float* Wh0 = (const float*)d_in[2];
  const float* b0  = (const float*)d_in[3];
  const float* Wx1 = (const float*)d_in[4];
  const float* Wh1 = (const float*)d_in[5];
  const float* b1  = (const float*)d_in[6];
  const float* Wf  = (const float*)d_in[7];
  const float* bf  = (const float*)d_in[8];

  const size_t MB = 1u << 20;
  const size_t OFF_W     = 0;            // 6 MiB weights
  const size_t OFF_XT    = 6 * MB;       // 1 MiB
  const size_t OFF_PHI   = 7 * MB;       // agent p ring: 8 x 256KB = 2 MiB
  const size_t OFF_PLO   = 9 * MB;
  const size_t OFF_QHI   = 11 * MB;      // agent q ring (fallback only)
  const size_t OFF_QLO   = 13 * MB;
  const size_t OFF_PART  = 15 * MB;      // 8 MiB
  const size_t OFF_PF    = 23 * MB;      // agent pf lines 64KB
  const size_t OFF_QF    = OFF_PF + 65536;        // agent qf lines 64KB
  const size_t OFF_XTAB  = OFF_QF + 65536;        // 1KB
  const size_t OFF_LF    = OFF_XTAB + 4096;       // local flag lines 48KB
  const size_t OFF_PLOCH = 24 * MB;      // local rings: 6 x 1 MiB
  const size_t OFF_PLOCL = 25 * MB;
  const size_t OFF_QLOCH = 26 * MB;
  const size_t OFF_QLOCL = 27 * MB;
  const size_t OFF_PIMPH = 28 * MB;
  const size_t OFF_PIMPL = 29 * MB;      // end 30 MiB

  char* ws = (char*)d_ws;
  f16* wsl = (f16*)(ws + OFF_W);
  float* xT = (float*)(ws + OFF_XT);
  unsigned short* phi = (unsigned short*)(ws + OFF_PHI);
  unsigned short* plo = (unsigned short*)(ws + OFF_PLO);
  unsigned short* qhi = (unsigned short*)(ws + OFF_QHI);
  unsigned short* qlo = (unsigned short*)(ws + OFF_QLO);
  float* part8 = (float*)(ws + OFF_PART);
  unsigned int* pfl = (unsigned int*)(ws + OFF_PF);
  unsigned int* qfl = (unsigned int*)(ws + OFF_QF);
  unsigned int* xtab = (unsigned int*)(ws + OFF_XTAB);
  unsigned int* lf  = (unsigned int*)(ws + OFF_LF);
  unsigned short* ploch = (unsigned short*)(ws + OFF_PLOCH);
  unsigned short* plocl = (unsigned short*)(ws + OFF_PLOCL);
  unsigned short* qloch = (unsigned short*)(ws + OFF_QLOCH);
  unsigned short* qlocl = (unsigned short*)(ws + OFF_QLOCL);
  unsigned short* pimph = (unsigned short*)(ws + OFF_PIMPH);
  unsigned short* pimpl = (unsigned short*)(ws + OFF_PIMPL);
  float* out = (float*)d_out;

  (void)hipFuncSetAttribute((const void*)lstm_main,
                            hipFuncAttributeMaxDynamicSharedMemorySize, 135168);

  // zero everything from agent rings through local rings (7..30 MiB)
  (void)hipMemsetAsync(ws + OFF_PHI, 0, 23 * MB, stream);

  prep_xT<<<1024, 256, 0, stream>>>(inp, xT);
  prep_w<<<12288, 256, 0, stream>>>(Wh0, Wx1, Wh1, wsl);

  lstm_main<<<256, 256, 135168, stream>>>(xT, wsl, Wx0, b0, b1, Wf,
                                          phi, plo, qhi, qlo, pfl, qfl,
                                          ploch, plocl, qloch, qlocl,
                                          pimph, pimpl, lf, xtab, part8);

  reduce_out<<<1024, 256, 0, stream>>>(part8, bf, out);
}

// Round 9
// 11475.677 us; speedup vs baseline: 1.1280x; 1.1280x over previous
//
#include <hip/hip_runtime.h>

// ============================================================================
// 2-layer LSTM (B=256, T=1024, H=512, in=1) + linear head. fp32 in/out.
//
// R13 = R11 (verified 9.66ms) + split-half pipelined consume. R12 (XCD-local
// L2 transport) regressed via VGPR-256 spill (WRITE 2.4GB) + extra serial
// legs -> reverted. Chain evidence: only latency-leg removal helps (R7 -21%).
// Remaining exposed legs on the consumer side: full-32-flag detect + second
// half of A-loads sit serially before MFMA though kt 0..7 needs slices 0..15
// only.
//  1. L0: poll pf[0..15] -> load kt0..7 -> MFMA kt0..7 (early non-blocking
//     SAMPLES of pf[16..31] + ring guard already in flight, hidden under
//     MFMA) -> check-else-poll -> load kt8..15 -> MFMA. Guard check moves to
//     just before the ring store.
//  2. L1: same split for qf / q-loads in phase 1; pf runahead gate unchanged.
//  3. All polls remain the R10/R11-verified per-line replica flags; math,
//     stores, drains, flags, epoch-inv bit-identical to R11 (absmax 6.1e-5).
// Predicted: 8.3-9.2ms, MfmaUtil ~15-16, VGPR <= ~190; neutral => producer
// drain/publish dominates -> tagged transport or latency floor.
// ============================================================================

typedef _Float16 f16;
typedef _Float16 f16x8 __attribute__((ext_vector_type(8)));
typedef float f32x4 __attribute__((ext_vector_type(4)));
typedef unsigned long long u64;

#define NB 256
#define NT_ 1024
#define NH 512
#define RING 16
#define SLOT (NB * NH)

__device__ __forceinline__ float sigm(float x)  { return 1.0f / (1.0f + __expf(-x)); }
__device__ __forceinline__ float tanhx(float x) { return 2.0f / (1.0f + __expf(-2.0f * x)) - 1.0f; }

// 8B agent-visible write-through store (verified R3..R11 transport primitive)
__device__ __forceinline__ void st8(unsigned short* p, u64 v) {
  __hip_atomic_store((u64*)p, v, __ATOMIC_RELAXED, __HIP_MEMORY_SCOPE_AGENT);
}
__device__ __forceinline__ void stf(unsigned* p, unsigned v) {
  __hip_atomic_store(p, v, __ATOMIC_RELAXED, __HIP_MEMORY_SCOPE_AGENT);
}
__device__ __forceinline__ unsigned ldf(const unsigned* p) {
  return __hip_atomic_load(p, __ATOMIC_RELAXED, __HIP_MEMORY_SCOPE_AGENT);
}
// Poll until every lane's flag (per-lane address/threshold) passes.
__device__ __forceinline__ unsigned pollr(const unsigned* a, unsigned thr) {
  unsigned v;
  for (;;) {
    v = ldf(a);
    if (!~__ballot(v >= thr)) break;
    __builtin_amdgcn_s_sleep(1);
  }
  asm volatile("" ::: "memory");
  return v;
}
// all-lanes-pass check for an early sample
__device__ __forceinline__ bool chk(unsigned v, unsigned thr) {
  return !~__ballot(v >= thr);
}

// flag line addressing: one 128B line (32 u32) per [chunk][slice<32][replica]
__device__ __forceinline__ unsigned* PFL(unsigned* pf, int c, int j, int r) {
  return pf + (((c * 32 + j) * 4) + r) * 32;
}
__device__ __forceinline__ unsigned* QFL(unsigned* qf, int c, int j, int r) {
  return qf + (((c * 32 + j) * 4) + r) * 32;
}

// ---------------------------------------------------------------------------
__global__ void prep_xT(const float* __restrict__ inp, float* __restrict__ xT) {
  int g = blockIdx.x * 256 + threadIdx.x;
  int t = g >> 8, b = g & 255;
  xT[t * NB + b] = inp[b * NT_ + t];
}

// ---------------------------------------------------------------------------
// fp32 -> fp16 weights, unified tiling (verified R11): 32 slices x
// [nh<2][jt<2][kt<16][lane<64][j<8]; slice = 32768 elems.
__global__ void prep_w(const float* __restrict__ Wh0,
                       const float* __restrict__ Wx1,
                       const float* __restrict__ Wh1,
                       f16* __restrict__ dst) {
  int g = blockIdx.x * 256 + threadIdx.x;   // 3 * 2^20 threads
  int mat = g >> 20;
  int r = g & 0xFFFFF;
  int j = r & 7, ln = (r >> 3) & 63, kt = (r >> 9) & 15;
  int cl = ln & 15, qd = ln >> 4;
  int k = kt * 32 + qd * 8 + j;
  int jt = (r >> 13) & 1, nh = (r >> 14) & 1, sl = (r >> 15) & 31;
  const float* W = (mat == 0) ? Wh0 : (mat == 1) ? Wx1 : Wh1;
  int gate = jt * 2 + (cl >> 3);
  int gcol = gate * 512 + sl * 16 + nh * 8 + (cl & 7);
  size_t di = (size_t)mat * 1048576 + (size_t)sl * 32768 +
              (((size_t)(nh * 2 + jt) * 16 + kt) * 64 + ln) * 8 + j;
  dst[di] = (f16)W[(size_t)k * 2048 + gcol];
}

// ---------------------------------------------------------------------------
__global__ void reduce_out(const float* __restrict__ part8,
                           const float* __restrict__ bfp,
                           float* __restrict__ out) {
  int g = blockIdx.x * 256 + threadIdx.x;   // 262144 = b*1024+t
  float v = bfp[0];
#pragma unroll
  for (int j = 0; j < 8; ++j) v += part8[(size_t)j * (NB * NT_) + g];
  out[g] = v;
}

// ---------------------------------------------------------------------------
// h transport layouts (slice-major, per-WG-contiguous; R7/R11-verified):
//   p[slot][c<4][sl<32][row<64][unit<16]  q[slot][c<4][sl<32][row<64][unit<16]
__global__ __launch_bounds__(256, 1) void lstm_main(
    const float* __restrict__ xT,       // [T][B]
    const f16*  __restrict__ wsl,       // tiled fp16 weights (6 MB)
    const float* __restrict__ wx0,      // [2048]
    const float* __restrict__ bias0,    // [2048]
    const float* __restrict__ bias1,    // [2048]
    const float* __restrict__ wf,       // [512]
    unsigned short* p_hi, unsigned short* p_lo,   // [RING][...] slice-major
    unsigned short* q_hi, unsigned short* q_lo,   // [RING][...] slice-major
    unsigned int* pf,                   // per-line flags [4c][32sl][4rep]x128B
    unsigned int* qf,                   // per-line flags [4c][32sl][4rep]x128B
    float* part8)                       // [8][B][T]
{
  extern __shared__ char smem[];
  const int tid = threadIdx.x;
  const int wv = tid >> 6, ln = tid & 63;
  const int qd = ln >> 4, cl = ln & 15;
  const int bx = blockIdx.x;
  const int r8 = bx & 7, idx = bx >> 3;
  const bool isL0 = !(r8 & 1);
  const int c = r8 >> 1;
  const int sl = idx;                   // 0..31 both layers
  const float LO = 1.0f / 1024.0f;
  const int u = cl & 7, g01 = cl >> 3;
  const bool hiH = (cl < 8);
  const int lr = wv * 16 + cl;          // chunk-local A row

  // ---- stage weight slice(s) into LDS (once) ----
  if (isL0) {
    const int4* s0 = (const int4*)wsl + (size_t)sl * 4096;           // 64 KB
    int4* d = (int4*)smem;
    for (int i = tid; i < 4096; i += 256) d[i] = s0[i];
  } else {
    const int4* s1 = (const int4*)wsl + 131072 + (size_t)sl * 4096;  // Wx1 64 KB
    const int4* s2 = (const int4*)wsl + 262144 + (size_t)sl * 4096;  // Wh1 64 KB
    int4* d = (int4*)smem;
    for (int i = tid; i < 4096; i += 256) { d[i] = s1[i]; d[4096 + i] = s2[i]; }
  }
  __syncthreads();

  if (isL0) {
    // ======== layer 0: p_s = LSTM(x_s, p_{s-1}) ========
    float w0a[2], w0b[2], b0a[2], b0b[2];
#pragma unroll
    for (int nh = 0; nh < 2; ++nh) {
      int base = sl * 16 + nh * 8 + u;
      w0a[nh] = wx0[g01 * 512 + base];
      b0a[nh] = bias0[g01 * 512 + base];
      w0b[nh] = wx0[(2 + g01) * 512 + base];
      b0b[nh] = bias0[(2 + g01) * 512 + base];
    }
    float cst[2][4] = {{0.f,0.f,0.f,0.f},{0.f,0.f,0.f,0.f}};
    // split-half poll addrs: first-half producers (flags 0..15, x4 replicas
    // sampled in parallel), second half (16..31), ring guard (qf 0..31 x2)
    const unsigned* pw0 = PFL(pf, c, ln & 15, (sl + (ln >> 4)) & 3);
    const unsigned* pw1 = PFL(pf, c, 16 + (ln & 15), (sl + (ln >> 4)) & 3);
    const unsigned* pwg = QFL(qf, c, ln & 31, (sl + (ln >> 5)) & 3);
    const f16x8* wl = (const f16x8*)smem;
    f16* sh  = (f16*)(smem + 65536);     // [64][16] hi stage (2 KB)
    f16* slo = sh + 1024;                // [64][16] lo stage (2 KB)

    for (int s = 0; s < NT_; ++s) {
      // ---- ring-epoch L1/L2 invalidate (addresses reused every 16 steps) ----
      if ((s & (RING - 1)) == 0 && s) {
        __syncthreads();
        if (wv == 0)
          asm volatile("buffer_inv sc1\n\ts_waitcnt vmcnt(0)" ::: "memory");
        __syncthreads();
      }
      const int slot_r = (s + RING - 1) & (RING - 1);   // h_{s-1}
      const int slot_w = s & (RING - 1);                // h_s
      // x prefetch — independent of flags, issue before the poll
      float4 xv = *(const float4*)(xT + s * NB + c * 64 + wv * 16 + qd * 4);
      // blocking: first-half producers done s-1
      if (s) pollr(pw0, (unsigned)s);
      // ---- A fragments first half (kt 0..7 -> slices 0..15) ----
      const f16* ah = (const f16*)p_hi + (size_t)slot_r * SLOT + (size_t)c * 32768 +
                      (qd >> 1) * 1024 + lr * 16 + (qd & 1) * 8;
      const f16* al = (const f16*)p_lo + (size_t)slot_r * SLOT + (size_t)c * 32768 +
                      (qd >> 1) * 1024 + lr * 16 + (qd & 1) * 8;
      f16x8 Ah[8], Al[8];
#pragma unroll
      for (int kt = 0; kt < 8; ++kt) {
        Ah[kt] = *(const f16x8*)(ah + kt * 2048);
        Al[kt] = *(const f16x8*)(al + kt * 2048);
      }
      // early samples: second-half flags + ring guard (latency hides under MFMA)
      unsigned v1 = s ? ldf(pw1) : 0xFFFFFFFFu;
      unsigned vg = ldf(pwg);
      f32x4 acc[4], accL[4];
#pragma unroll
      for (int t4 = 0; t4 < 4; ++t4) {
        acc[t4] = (f32x4){0.f,0.f,0.f,0.f};
        accL[t4] = (f32x4){0.f,0.f,0.f,0.f};
      }
#pragma unroll
      for (int kt = 0; kt < 8; ++kt) {
#pragma unroll
        for (int t4 = 0; t4 < 4; ++t4) {                 // t4 = nh*2 + jt
          f16x8 bw = wl[(t4 * 16 + kt) * 64 + ln];
          acc[t4]  = __builtin_amdgcn_mfma_f32_16x16x32_f16(Ah[kt], bw, acc[t4], 0, 0, 0);
          accL[t4] = __builtin_amdgcn_mfma_f32_16x16x32_f16(Al[kt], bw, accL[t4], 0, 0, 0);
        }
      }
      // confirm second-half producers, then load + MFMA kt 8..15
      if (s && !chk(v1, (unsigned)s)) pollr(pw1, (unsigned)s);
      asm volatile("" ::: "memory");
      f16x8 Bh[8], Bl[8];
#pragma unroll
      for (int kt = 0; kt < 8; ++kt) {
        Bh[kt] = *(const f16x8*)(ah + (kt + 8) * 2048);
        Bl[kt] = *(const f16x8*)(al + (kt + 8) * 2048);
      }
#pragma unroll
      for (int kt = 0; kt < 8; ++kt) {
#pragma unroll
        for (int t4 = 0; t4 < 4; ++t4) {
          f16x8 bw = wl[(t4 * 16 + (kt + 8)) * 64 + ln];
          acc[t4]  = __builtin_amdgcn_mfma_f32_16x16x32_f16(Bh[kt], bw, acc[t4], 0, 0, 0);
          accL[t4] = __builtin_amdgcn_mfma_f32_16x16x32_f16(Bl[kt], bw, accL[t4], 0, 0, 0);
        }
      }
      // ---- epilogue (shfl-swap gate assembly) -> LDS stage ----
#pragma unroll
      for (int e = 0; e < 4; ++e) {
        float xe = (e == 0) ? xv.x : (e == 1) ? xv.y : (e == 2) ? xv.z : xv.w;
        int r = wv * 16 + qd * 4 + e;
#pragma unroll
        for (int nh = 0; nh < 2; ++nh) {
          float v0 = acc[nh*2+0][e] + accL[nh*2+0][e] * LO + xe * w0a[nh] + b0a[nh]; // i/f
          float v1g = acc[nh*2+1][e] + accL[nh*2+1][e] * LO + xe * w0b[nh] + b0b[nh]; // g/o
          float w0 = __shfl_xor(v0, 8, 16);
          float w1 = __shfl_xor(v1g, 8, 16);
          float gi = hiH ? v0 : w0;
          float gf = hiH ? w0 : v0;
          float gg = hiH ? v1g : w1;
          float go = hiH ? w1 : v1g;
          float ii = sigm(gi), ff = sigm(gf), tg = tanhx(gg), oo = sigm(go);
          cst[nh][e] = ff * cst[nh][e] + ii * tg;
          float h = oo * tanhx(cst[nh][e]);
          int su = r * 16 + nh * 8 + u;
          if (hiH) {
            sh[su] = (f16)h;
          } else {
            f16 hh = (f16)h;
            slo[su] = (f16)((h - (float)hh) * 1024.0f);
          }
        }
      }
      __syncthreads();
      // ring-overwrite guard (early-sampled; usually already satisfied)
      unsigned thrG = (s >= RING) ? (unsigned)(s - RING + 1) : 0u;
      if (!chk(vg, thrG)) pollr(pwg, thrG);
      asm volatile("" ::: "memory");
      // ---- coop store: 2 x 2KB contiguous, 8B/lane, full-line coverage ----
      {
        unsigned short* bh = p_hi + (size_t)slot_w * SLOT + (size_t)c * 32768 + (size_t)sl * 1024;
        unsigned short* bl = p_lo + (size_t)slot_w * SLOT + (size_t)c * 32768 + (size_t)sl * 1024;
#pragma unroll
        for (int i = tid; i < 512; i += 256) {
          int strm = i >> 8, pc = i & 255;               // 8B piece index
          const f16* src = (strm ? slo : sh) + pc * 4;
          st8((strm ? bl : bh) + pc * 4, *(const u64*)src);
        }
      }
      __syncthreads();   // all waves' stores vmcnt-drained at LLC before barrier
      if (tid < 4)       // 4 replica flags, each on its OWN 128B line
        stf(PFL(pf, c, sl, tid), (unsigned)(s + 1));
    }
  } else {
    // ======== layer 1: q_s = LSTM(p_s, q_{s-1}) ========
    float b1c0[2], b1c1[2], wfv[2];
#pragma unroll
    for (int nh = 0; nh < 2; ++nh) {
      int base = sl * 16 + nh * 8 + u;
      b1c0[nh] = bias1[g01 * 512 + base];
      b1c1[nh] = bias1[(2 + g01) * 512 + base];
      wfv[nh] = wf[base];
    }
    float cst[2][4] = {{0.f,0.f,0.f,0.f},{0.f,0.f,0.f,0.f}};
    // front combined read: lanes 0-15 qf[0..15] (blocking, thr s), lanes
    // 16-31 same flags replica+1 (blocking), lanes 32-63 pf[0..31]
    // (advisory, thr s+1 -> fresh full-coverage runahead gate).
    const unsigned* a_init = (ln < 16) ? QFL(qf, c, ln, sl & 3)
                           : (ln < 32) ? QFL(qf, c, ln - 16, (sl + 1) & 3)
                                       : PFL(pf, c, ln - 32, sl & 3);
    const unsigned* qw1 = QFL(qf, c, 16 + (ln & 15), (sl + (ln >> 4)) & 3);
    const unsigned* pwA = PFL(pf, c, ln & 31, (sl + (ln >> 5)) & 3);
    const f16x8* wx_ = (const f16x8*)smem;
    const f16x8* wh_ = (const f16x8*)(smem + 65536);
    f16* sh  = (f16*)(smem + 131072);   // [64][16] hi stage (2 KB)
    f16* slo = sh + 1024;               // [64][16] lo stage (2 KB)

    for (int s = 0; s < NT_; ++s) {
      if ((s & (RING - 1)) == 0 && s) {
        __syncthreads();
        if (wv == 0)
          asm volatile("buffer_inv sc1\n\ts_waitcnt vmcnt(0)" ::: "memory");
        __syncthreads();
      }
      const int slot_r = (s + RING - 1) & (RING - 1);
      const int slot_w = s & (RING - 1);
      // blocking qf[0..15] poll (peers done s-1) + advisory fresh pf view
      bool early = false;
      if (s) {
        unsigned thr_i = (ln < 32) ? (unsigned)s : (unsigned)(s + 1);
        unsigned v = ldf(a_init);
        u64 bal = __ballot(v >= thr_i);
        while ((unsigned)bal != 0xFFFFFFFFu) {
          __builtin_amdgcn_s_sleep(1);
          v = ldf(a_init);
          bal = __ballot(v >= thr_i);
        }
        asm volatile("" ::: "memory");
        early = ((unsigned)(bal >> 32) == 0xFFFFFFFFu);
      }
      // q fragments first half (kt 0..7 -> slices 0..15)
      const f16* aqh = (const f16*)q_hi + (size_t)slot_r * SLOT + (size_t)c * 32768 +
                       (qd >> 1) * 1024 + lr * 16 + (qd & 1) * 8;
      const f16* aql = (const f16*)q_lo + (size_t)slot_r * SLOT + (size_t)c * 32768 +
                       (qd >> 1) * 1024 + lr * 16 + (qd & 1) * 8;
      f16x8 Aq[8][2];
#pragma unroll
      for (int kt = 0; kt < 8; ++kt) {
        Aq[kt][0] = *(const f16x8*)(aqh + kt * 2048);
        Aq[kt][1] = *(const f16x8*)(aql + kt * 2048);
      }
      // runahead: fresh pf view showed L0 done step s -> issue p loads NOW
      const f16* aph = (const f16*)p_hi + (size_t)slot_w * SLOT + (size_t)c * 32768 +
                       (qd >> 1) * 1024 + lr * 16 + (qd & 1) * 8;
      const f16* apl = (const f16*)p_lo + (size_t)slot_w * SLOT + (size_t)c * 32768 +
                       (qd >> 1) * 1024 + lr * 16 + (qd & 1) * 8;
      f16x8 Ap[16][2];
      if (early) {
#pragma unroll
        for (int kt = 0; kt < 16; ++kt) {
          Ap[kt][0] = *(const f16x8*)(aph + kt * 2048);
          Ap[kt][1] = *(const f16x8*)(apl + kt * 2048);
        }
      }
      // early sample of qf second half (hides under phase-1 first half)
      unsigned vq1 = s ? ldf(qw1) : 0xFFFFFFFFu;
      f32x4 acc[4], accL[4];
#pragma unroll
      for (int t4 = 0; t4 < 4; ++t4) {
        acc[t4] = (f32x4){0.f,0.f,0.f,0.f};
        accL[t4] = (f32x4){0.f,0.f,0.f,0.f};
      }
      // phase 1a: q_{s-1} @ Wh1, kt 0..7
#pragma unroll
      for (int kt = 0; kt < 8; ++kt) {
#pragma unroll
        for (int t4 = 0; t4 < 4; ++t4) {
          f16x8 bw = wh_[(t4 * 16 + kt) * 64 + ln];
          acc[t4]  = __builtin_amdgcn_mfma_f32_16x16x32_f16(Aq[kt][0], bw, acc[t4], 0, 0, 0);
          accL[t4] = __builtin_amdgcn_mfma_f32_16x16x32_f16(Aq[kt][1], bw, accL[t4], 0, 0, 0);
        }
      }
      // confirm qf[16..31], load + MFMA kt 8..15
      if (s && !chk(vq1, (unsigned)s)) pollr(qw1, (unsigned)s);
      asm volatile("" ::: "memory");
      f16x8 Bq[8][2];
#pragma unroll
      for (int kt = 0; kt < 8; ++kt) {
        Bq[kt][0] = *(const f16x8*)(aqh + (kt + 8) * 2048);
        Bq[kt][1] = *(const f16x8*)(aql + (kt + 8) * 2048);
      }
#pragma unroll
      for (int kt = 0; kt < 8; ++kt) {
#pragma unroll
        for (int t4 = 0; t4 < 4; ++t4) {
          f16x8 bw = wh_[(t4 * 16 + (kt + 8)) * 64 + ln];
          acc[t4]  = __builtin_amdgcn_mfma_f32_16x16x32_f16(Bq[kt][0], bw, acc[t4], 0, 0, 0);
          accL[t4] = __builtin_amdgcn_mfma_f32_16x16x32_f16(Bq[kt][1], bw, accL[t4], 0, 0, 0);
        }
      }
      if (!early) {
        pollr(pwA, (unsigned)(s + 1));
#pragma unroll
        for (int kt = 0; kt < 16; ++kt) {
          Ap[kt][0] = *(const f16x8*)(aph + kt * 2048);
          Ap[kt][1] = *(const f16x8*)(apl + kt * 2048);
        }
      }
      // phase 2: p_s @ Wx1
#pragma unroll
      for (int kt = 0; kt < 16; ++kt) {
#pragma unroll
        for (int t4 = 0; t4 < 4; ++t4) {
          f16x8 bw = wx_[(t4 * 16 + kt) * 64 + ln];
          acc[t4]  = __builtin_amdgcn_mfma_f32_16x16x32_f16(Ap[kt][0], bw, acc[t4], 0, 0, 0);
          accL[t4] = __builtin_amdgcn_mfma_f32_16x16x32_f16(Ap[kt][1], bw, accL[t4], 0, 0, 0);
        }
      }
      // ---- epilogue -> LDS stage ----
      float po[4];
#pragma unroll
      for (int e = 0; e < 4; ++e) {
        po[e] = 0.0f;
#pragma unroll
        for (int nh = 0; nh < 2; ++nh) {
          float v0 = acc[nh*2+0][e] + accL[nh*2+0][e] * LO + b1c0[nh];   // i / f
          float v1g = acc[nh*2+1][e] + accL[nh*2+1][e] * LO + b1c1[nh];  // g / o
          float w0 = __shfl_xor(v0, 8, 16);
          float w1 = __shfl_xor(v1g, 8, 16);
          float gi = hiH ? v0 : w0;
          float gf = hiH ? w0 : v0;
          float gg = hiH ? v1g : w1;
          float go = hiH ? w1 : v1g;
          float ii = sigm(gi), ff = sigm(gf), tg = tanhx(gg), oo = sigm(go);
          cst[nh][e] = ff * cst[nh][e] + ii * tg;
          float h = oo * tanhx(cst[nh][e]);
          int su = (wv * 16 + qd * 4 + e) * 16 + nh * 8 + u;
          if (hiH) {
            sh[su] = (f16)h;
          } else {
            f16 hh = (f16)h;
            slo[su] = (f16)((h - (float)hh) * 1024.0f);
          }
          po[e] += hiH ? wfv[nh] * h : 0.0f;
        }
      }
      __syncthreads();
      // ---- coop store: 2 x 2KB contiguous, 8B/lane, full-line coverage ----
      {
        unsigned short* bhq = q_hi + (size_t)slot_w * SLOT + (size_t)c * 32768 + (size_t)sl * 1024;
        unsigned short* blq = q_lo + (size_t)slot_w * SLOT + (size_t)c * 32768 + (size_t)sl * 1024;
#pragma unroll
        for (int i = tid; i < 512; i += 256) {
          int strm = i >> 8, pc = i & 255;               // 8B piece index
          const f16* src = (strm ? slo : sh) + pc * 4;
          st8((strm ? blq : bhq) + pc * 4, *(const u64*)src);
        }
      }
      __syncthreads();   // stores drained at LLC
      if (tid < 4)       // 4 replica flags, each on its OWN 128B line
        stf(QFL(qf, c, sl, tid), (unsigned)(s + 1));
      // deferred head-output reduce + atomic (off the q->q critical path)
#pragma unroll
      for (int e = 0; e < 4; ++e) {
        float r = po[e];
#pragma unroll
        for (int m = 1; m < 16; m <<= 1) r += __shfl_xor(r, m, 16);
        if (cl == 0)
          atomicAdd(part8 + (size_t)(sl & 7) * (NB * NT_) +
                        (size_t)(c * 64 + wv * 16 + qd * 4 + e) * NT_ + s, r);
      }
    }
  }
}

// ---------------------------------------------------------------------------
extern "C" void kernel_launch(void* const* d_in, const int* in_sizes, int n_in,
                              void* d_out, int out_size, void* d_ws, size_t ws_size,
                              hipStream_t stream) {
  (void)in_sizes; (void)n_in; (void)out_size; (void)ws_size;
  const float* inp = (const float*)d_in[0];
  const float* Wx0 = (const float*)d_in[1];
  const float* Wh0 = (const float*)d_in[2];
  const float* b0  = (const float*)d_in[3];
  const float* Wx1 = (const float*)d_in[4];
  const float* Wh1 = (const float*)d_in[5];
  const float* b1  = (const float*)d_in[6];
  const float* Wf  = (const float*)d_in[7];
  const float* bf  = (const float*)d_in[8];

  const size_t MB = 1u << 20;
  const size_t OFF_W    = 0;                 // 6 MiB tiled fp16 weights
  const size_t OFF_XT   = 6 * MB;            // 1 MiB
  const size_t OFF_PHI  = 7 * MB;            // 4 MiB (RING x 256 KB)
  const size_t OFF_PLO  = 11 * MB;
  const size_t OFF_QHI  = 15 * MB;
  const size_t OFF_QLO  = 19 * MB;
  const size_t OFF_PART = 23 * MB;           // 8 MiB
  const size_t OFF_CTR  = 31 * MB;           // flags: pf 64KB + qf 64KB

  char* ws = (char*)d_ws;
  f16* wsl = (f16*)(ws + OFF_W);
  float* xT = (float*)(ws + OFF_XT);
  unsigned short* phi = (unsigned short*)(ws + OFF_PHI);
  unsigned short* plo = (unsigned short*)(ws + OFF_PLO);
  unsigned short* qhi = (unsigned short*)(ws + OFF_QHI);
  unsigned short* qlo = (unsigned short*)(ws + OFF_QLO);
  float* part8 = (float*)(ws + OFF_PART);
  unsigned int* pfl = (unsigned int*)(ws + OFF_CTR);
  unsigned int* qfl = pfl + 16384;           // pf = 512 lines * 32 u32
  float* out = (float*)d_out;

  (void)hipFuncSetAttribute((const void*)lstm_main,
                            hipFuncAttributeMaxDynamicSharedMemorySize, 135168);

  // zero rings + partials + flags (contiguous; flags 128 KB)
  (void)hipMemsetAsync(ws + OFF_PHI, 0, (OFF_CTR + 131072) - OFF_PHI, stream);

  prep_xT<<<1024, 256, 0, stream>>>(inp, xT);
  prep_w<<<12288, 256, 0, stream>>>(Wh0, Wx1, Wh1, wsl);

  lstm_main<<<256, 256, 135168, stream>>>(xT, wsl, Wx0, b0, b1, Wf,
                                          phi, plo, qhi, qlo, pfl, qfl, part8);

  reduce_out<<<1024, 256, 0, stream>>>(part8, bf, out);
}

// Round 10
// 10391.852 us; speedup vs baseline: 1.2457x; 1.1043x over previous
//
#include <hip/hip_runtime.h>

// ============================================================================
// 2-layer LSTM (B=256, T=1024, H=512, in=1) + linear head. fp32 in/out.
//
// R14 = R11 (verified 9.66ms) + per-wave autonomy (zero barriers in loop).
// R13 (split-half consume) regressed -19%: splitting the 32-load batch
// halves memory-level parallelism on the fill leg -> two serial fill RTs.
// Consumer structure reverted to R11 (batched poll, batched loads).
// Remaining coupling: 2x __syncthreads/step couple the 4 waves -> WG flag
// waits slowest wave; consumers wait slowest WG; straggler jitter compounds
// into the period. Fix exploits layout luck: slice rows are ALREADY
// wave-contiguous (wave wv's 16 rows = bytes wv*512..+511 of each slice).
//  - Producer: wave-private LDS stage (ds_write -> lgkmcnt(0) -> ds_read, no
//    barrier within a wave), ONE 8Bx64 full-line store per stream (512B),
//    per-wave vmcnt drain, per-wave flag pf[c][sl][wv] (flag replica dim
//    repurposed -> same 64KB footprint; R9/R10 proved replicas useless).
//  - Consumer wave wv polls exactly the 32 wave-wv flags its rows depend on
//    (lanes 0-31), guard/advisory on lanes 32-63 as R11.
//  - Epoch buffer_inv sc1 made wave-local (no barriers around it).
//  - Weight staging barrier (one-time) kept. Math bit-identical (absmax
//    6.103516e-05 expected EXACT).
// Predicted: 8.0-8.8ms, MfmaUtil ~15-16, VGPR ~180; neutral => chain is pure
// fabric RTs -> tagged transport or latency floor next.
// ============================================================================

typedef _Float16 f16;
typedef _Float16 f16x8 __attribute__((ext_vector_type(8)));
typedef float f32x4 __attribute__((ext_vector_type(4)));
typedef unsigned long long u64;

#define NB 256
#define NT_ 1024
#define NH 512
#define RING 16
#define SLOT (NB * NH)

__device__ __forceinline__ float sigm(float x)  { return 1.0f / (1.0f + __expf(-x)); }
__device__ __forceinline__ float tanhx(float x) { return 2.0f / (1.0f + __expf(-2.0f * x)) - 1.0f; }

// 8B agent-visible write-through store (verified R3..R11 transport primitive)
__device__ __forceinline__ void st8(unsigned short* p, u64 v) {
  __hip_atomic_store((u64*)p, v, __ATOMIC_RELAXED, __HIP_MEMORY_SCOPE_AGENT);
}
__device__ __forceinline__ void stf(unsigned* p, unsigned v) {
  __hip_atomic_store(p, v, __ATOMIC_RELAXED, __HIP_MEMORY_SCOPE_AGENT);
}
__device__ __forceinline__ unsigned ldf(const unsigned* p) {
  return __hip_atomic_load(p, __ATOMIC_RELAXED, __HIP_MEMORY_SCOPE_AGENT);
}
// Poll until every lane's flag (per-lane address/threshold) passes.
__device__ __forceinline__ unsigned pollr(const unsigned* a, unsigned thr) {
  unsigned v;
  for (;;) {
    v = ldf(a);
    if (!~__ballot(v >= thr)) break;
    __builtin_amdgcn_s_sleep(1);
  }
  asm volatile("" ::: "memory");
  return v;
}

// flag line addressing: one 128B line (32 u32) per [chunk][slice<32][wave<4]
__device__ __forceinline__ unsigned* PFL(unsigned* pf, int c, int j, int w) {
  return pf + (((c * 32 + j) * 4) + w) * 32;
}
__device__ __forceinline__ unsigned* QFL(unsigned* qf, int c, int j, int w) {
  return qf + (((c * 32 + j) * 4) + w) * 32;
}

// ---------------------------------------------------------------------------
__global__ void prep_xT(const float* __restrict__ inp, float* __restrict__ xT) {
  int g = blockIdx.x * 256 + threadIdx.x;
  int t = g >> 8, b = g & 255;
  xT[t * NB + b] = inp[b * NT_ + t];
}

// ---------------------------------------------------------------------------
// fp32 -> fp16 weights, unified tiling (verified R11): 32 slices x
// [nh<2][jt<2][kt<16][lane<64][j<8]; slice = 32768 elems.
__global__ void prep_w(const float* __restrict__ Wh0,
                       const float* __restrict__ Wx1,
                       const float* __restrict__ Wh1,
                       f16* __restrict__ dst) {
  int g = blockIdx.x * 256 + threadIdx.x;   // 3 * 2^20 threads
  int mat = g >> 20;
  int r = g & 0xFFFFF;
  int j = r & 7, ln = (r >> 3) & 63, kt = (r >> 9) & 15;
  int cl = ln & 15, qd = ln >> 4;
  int k = kt * 32 + qd * 8 + j;
  int jt = (r >> 13) & 1, nh = (r >> 14) & 1, sl = (r >> 15) & 31;
  const float* W = (mat == 0) ? Wh0 : (mat == 1) ? Wx1 : Wh1;
  int gate = jt * 2 + (cl >> 3);
  int gcol = gate * 512 + sl * 16 + nh * 8 + (cl & 7);
  size_t di = (size_t)mat * 1048576 + (size_t)sl * 32768 +
              (((size_t)(nh * 2 + jt) * 16 + kt) * 64 + ln) * 8 + j;
  dst[di] = (f16)W[(size_t)k * 2048 + gcol];
}

// ---------------------------------------------------------------------------
__global__ void reduce_out(const float* __restrict__ part8,
                           const float* __restrict__ bfp,
                           float* __restrict__ out) {
  int g = blockIdx.x * 256 + threadIdx.x;   // 262144 = b*1024+t
  float v = bfp[0];
#pragma unroll
  for (int j = 0; j < 8; ++j) v += part8[(size_t)j * (NB * NT_) + g];
  out[g] = v;
}

// ---------------------------------------------------------------------------
// h transport layouts (slice-major, rows wave-contiguous; R7/R11-verified):
//   p[slot][c<4][sl<32][row<64][unit<16]  q[slot][c<4][sl<32][row<64][unit<16]
// wave wv's block = rows 16wv..16wv+15 = bytes wv*512..+511 of each slice.
__global__ __launch_bounds__(256, 1) void lstm_main(
    const float* __restrict__ xT,       // [T][B]
    const f16*  __restrict__ wsl,       // tiled fp16 weights (6 MB)
    const float* __restrict__ wx0,      // [2048]
    const float* __restrict__ bias0,    // [2048]
    const float* __restrict__ bias1,    // [2048]
    const float* __restrict__ wf,       // [512]
    unsigned short* p_hi, unsigned short* p_lo,   // [RING][...] slice-major
    unsigned short* q_hi, unsigned short* q_lo,   // [RING][...] slice-major
    unsigned int* pf,                   // per-line flags [4c][32sl][4wv]x128B
    unsigned int* qf,                   // per-line flags [4c][32sl][4wv]x128B
    float* part8)                       // [8][B][T]
{
  extern __shared__ char smem[];
  const int tid = threadIdx.x;
  const int wv = tid >> 6, ln = tid & 63;
  const int qd = ln >> 4, cl = ln & 15;
  const int bx = blockIdx.x;
  const int r8 = bx & 7, idx = bx >> 3;
  const bool isL0 = !(r8 & 1);
  const int c = r8 >> 1;
  const int sl = idx;                   // 0..31 both layers
  const float LO = 1.0f / 1024.0f;
  const int u = cl & 7, g01 = cl >> 3;
  const bool hiH = (cl < 8);
  const int lr = wv * 16 + cl;          // chunk-local A row

  // ---- stage weight slice(s) into LDS (once; one-time barrier kept) ----
  if (isL0) {
    const int4* s0 = (const int4*)wsl + (size_t)sl * 4096;           // 64 KB
    int4* d = (int4*)smem;
    for (int i = tid; i < 4096; i += 256) d[i] = s0[i];
  } else {
    const int4* s1 = (const int4*)wsl + 131072 + (size_t)sl * 4096;  // Wx1 64 KB
    const int4* s2 = (const int4*)wsl + 262144 + (size_t)sl * 4096;  // Wh1 64 KB
    int4* d = (int4*)smem;
    for (int i = tid; i < 4096; i += 256) { d[i] = s1[i]; d[4096 + i] = s2[i]; }
  }
  __syncthreads();

  if (isL0) {
    // ======== layer 0: p_s = LSTM(x_s, p_{s-1}) — wave-autonomous ========
    float w0a[2], w0b[2], b0a[2], b0b[2];
#pragma unroll
    for (int nh = 0; nh < 2; ++nh) {
      int base = sl * 16 + nh * 8 + u;
      w0a[nh] = wx0[g01 * 512 + base];
      b0a[nh] = bias0[g01 * 512 + base];
      w0b[nh] = wx0[(2 + g01) * 512 + base];
      b0b[nh] = bias0[(2 + g01) * 512 + base];
    }
    float cst[2][4] = {{0.f,0.f,0.f,0.f},{0.f,0.f,0.f,0.f}};
    // per-wave poll: lanes 0-31 -> pf[ln][wv] >= s (peer waves done s-1),
    // lanes 32-63 -> qf[ln-32][wv] >= s-RING+1 (ring-overwrite guard: L1
    // wave-wv readers of our block are past slot-old).
    const unsigned* pwa = (ln < 32) ? PFL(pf, c, ln, wv)
                                    : QFL(qf, c, ln - 32, wv);
    const f16x8* wl = (const f16x8*)smem;
    f16* shW  = (f16*)(smem + 65536) + wv * 256;         // wave-private hi
    f16* sloW = (f16*)(smem + 65536) + 1024 + wv * 256;  // wave-private lo

    for (int s = 0; s < NT_; ++s) {
      // ---- ring-epoch invalidate, wave-local (no barriers) ----
      if ((s & (RING - 1)) == 0 && s)
        asm volatile("buffer_inv sc1\n\ts_waitcnt vmcnt(0)" ::: "memory");
      const int slot_r = (s + RING - 1) & (RING - 1);   // h_{s-1}
      const int slot_w = s & (RING - 1);                // h_s
      // x prefetch — independent of flags, issue before the poll
      float4 xv = *(const float4*)(xT + s * NB + c * 64 + wv * 16 + qd * 4);
      if (s) {
        unsigned thr = (ln < 32) ? (unsigned)s
                                 : (s >= RING ? (unsigned)(s - RING + 1) : 0u);
        pollr(pwa, thr);
      }
      // ---- A fragments (p_{s-1} hi/lo): batched 32-load fill (R11 style) ----
      const f16* ah = (const f16*)p_hi + (size_t)slot_r * SLOT + (size_t)c * 32768 +
                      (qd >> 1) * 1024 + lr * 16 + (qd & 1) * 8;
      const f16* al = (const f16*)p_lo + (size_t)slot_r * SLOT + (size_t)c * 32768 +
                      (qd >> 1) * 1024 + lr * 16 + (qd & 1) * 8;
      f16x8 Ah[16], Al[16];
#pragma unroll
      for (int kt = 0; kt < 16; ++kt) {
        Ah[kt] = *(const f16x8*)(ah + kt * 2048);
        Al[kt] = *(const f16x8*)(al + kt * 2048);
      }
      f32x4 acc[4], accL[4];
#pragma unroll
      for (int t4 = 0; t4 < 4; ++t4) {
        acc[t4] = (f32x4){0.f,0.f,0.f,0.f};
        accL[t4] = (f32x4){0.f,0.f,0.f,0.f};
      }
#pragma unroll
      for (int kt = 0; kt < 16; ++kt) {
#pragma unroll
        for (int t4 = 0; t4 < 4; ++t4) {                 // t4 = nh*2 + jt
          f16x8 bw = wl[(t4 * 16 + kt) * 64 + ln];
          acc[t4]  = __builtin_amdgcn_mfma_f32_16x16x32_f16(Ah[kt], bw, acc[t4], 0, 0, 0);
          accL[t4] = __builtin_amdgcn_mfma_f32_16x16x32_f16(Al[kt], bw, accL[t4], 0, 0, 0);
        }
      }
      // ---- epilogue (shfl-swap gate assembly) -> wave-private LDS stage ----
#pragma unroll
      for (int e = 0; e < 4; ++e) {
        float xe = (e == 0) ? xv.x : (e == 1) ? xv.y : (e == 2) ? xv.z : xv.w;
#pragma unroll
        for (int nh = 0; nh < 2; ++nh) {
          float v0 = acc[nh*2+0][e] + accL[nh*2+0][e] * LO + xe * w0a[nh] + b0a[nh]; // i/f
          float v1 = acc[nh*2+1][e] + accL[nh*2+1][e] * LO + xe * w0b[nh] + b0b[nh]; // g/o
          float w0 = __shfl_xor(v0, 8, 16);
          float w1 = __shfl_xor(v1, 8, 16);
          float gi = hiH ? v0 : w0;
          float gf = hiH ? w0 : v0;
          float gg = hiH ? v1 : w1;
          float go = hiH ? w1 : v1;
          float ii = sigm(gi), ff = sigm(gf), tg = tanhx(gg), oo = sigm(go);
          cst[nh][e] = ff * cst[nh][e] + ii * tg;
          float h = oo * tanhx(cst[nh][e]);
          int su = (qd * 4 + e) * 16 + nh * 8 + u;       // wave-local index
          if (hiH) {
            shW[su] = (f16)h;
          } else {
            f16 hh = (f16)h;
            sloW[su] = (f16)((h - (float)hh) * 1024.0f);
          }
        }
      }
      // wave-local LDS transpose fence (no barrier: same-wave ds ordering)
      asm volatile("s_waitcnt lgkmcnt(0)" ::: "memory");
      // ---- wave store: 512B hi + 512B lo, 8B/lane, full-line coverage ----
      {
        size_t boff = (size_t)slot_w * SLOT + (size_t)c * 32768 +
                      (size_t)sl * 1024 + wv * 256;
        st8(p_hi + boff + ln * 4, *(const u64*)(shW + ln * 4));
        st8(p_lo + boff + ln * 4, *(const u64*)(sloW + ln * 4));
      }
      asm volatile("s_waitcnt vmcnt(0)" ::: "memory");   // per-wave drain
      if (ln == 0) stf(PFL(pf, c, sl, wv), (unsigned)(s + 1));
    }
  } else {
    // ======== layer 1: q_s = LSTM(p_s, q_{s-1}) — wave-autonomous ========
    float b1c0[2], b1c1[2], wfv[2];
#pragma unroll
    for (int nh = 0; nh < 2; ++nh) {
      int base = sl * 16 + nh * 8 + u;
      b1c0[nh] = bias1[g01 * 512 + base];
      b1c1[nh] = bias1[(2 + g01) * 512 + base];
      wfv[nh] = wf[base];
    }
    float cst[2][4] = {{0.f,0.f,0.f,0.f},{0.f,0.f,0.f,0.f}};
    // per-wave combined read: lanes 0-31 qf[ln][wv] (blocking, thr s),
    // lanes 32-63 pf[ln-32][wv] (advisory, thr s+1 -> runahead gate).
    const unsigned* a_init = (ln < 32) ? QFL(qf, c, ln, wv)
                                       : PFL(pf, c, ln - 32, wv);
    // straggler pf poll (2 lanes per flag; harmless dup)
    const unsigned* ppf = PFL(pf, c, ln & 31, wv);
    const f16x8* wx_ = (const f16x8*)smem;
    const f16x8* wh_ = (const f16x8*)(smem + 65536);
    f16* shW  = (f16*)(smem + 131072) + wv * 256;        // wave-private hi
    f16* sloW = (f16*)(smem + 131072) + 1024 + wv * 256; // wave-private lo

    for (int s = 0; s < NT_; ++s) {
      if ((s & (RING - 1)) == 0 && s)
        asm volatile("buffer_inv sc1\n\ts_waitcnt vmcnt(0)" ::: "memory");
      const int slot_r = (s + RING - 1) & (RING - 1);
      const int slot_w = s & (RING - 1);
      // blocking qf poll (peer waves done s-1) + advisory fresh pf view
      bool early = false;
      if (s) {
        unsigned thr_i = (ln < 32) ? (unsigned)s : (unsigned)(s + 1);
        unsigned v = ldf(a_init);
        u64 bal = __ballot(v >= thr_i);
        while ((unsigned)bal != 0xFFFFFFFFu) {
          __builtin_amdgcn_s_sleep(1);
          v = ldf(a_init);
          bal = __ballot(v >= thr_i);
        }
        asm volatile("" ::: "memory");
        early = ((unsigned)(bal >> 32) == 0xFFFFFFFFu);
      }
      // preload q_{s-1} fragments (batched)
      const f16* aqh = (const f16*)q_hi + (size_t)slot_r * SLOT + (size_t)c * 32768 +
                       (qd >> 1) * 1024 + lr * 16 + (qd & 1) * 8;
      const f16* aql = (const f16*)q_lo + (size_t)slot_r * SLOT + (size_t)c * 32768 +
                       (qd >> 1) * 1024 + lr * 16 + (qd & 1) * 8;
      f16x8 Aq[16][2];
#pragma unroll
      for (int kt = 0; kt < 16; ++kt) {
        Aq[kt][0] = *(const f16x8*)(aqh + kt * 2048);
        Aq[kt][1] = *(const f16x8*)(aql + kt * 2048);
      }
      // runahead: fresh pf view showed L0 done step s -> issue p loads NOW
      const f16* aph = (const f16*)p_hi + (size_t)slot_w * SLOT + (size_t)c * 32768 +
                       (qd >> 1) * 1024 + lr * 16 + (qd & 1) * 8;
      const f16* apl = (const f16*)p_lo + (size_t)slot_w * SLOT + (size_t)c * 32768 +
                       (qd >> 1) * 1024 + lr * 16 + (qd & 1) * 8;
      f16x8 Ap[16][2];
      if (early) {
#pragma unroll
        for (int kt = 0; kt < 16; ++kt) {
          Ap[kt][0] = *(const f16x8*)(aph + kt * 2048);
          Ap[kt][1] = *(const f16x8*)(apl + kt * 2048);
        }
      }
      f32x4 acc[4], accL[4];
#pragma unroll
      for (int t4 = 0; t4 < 4; ++t4) {
        acc[t4] = (f32x4){0.f,0.f,0.f,0.f};
        accL[t4] = (f32x4){0.f,0.f,0.f,0.f};
      }
      // phase 1: q_{s-1} @ Wh1
#pragma unroll
      for (int kt = 0; kt < 16; ++kt) {
#pragma unroll
        for (int t4 = 0; t4 < 4; ++t4) {
          f16x8 bw = wh_[(t4 * 16 + kt) * 64 + ln];
          acc[t4]  = __builtin_amdgcn_mfma_f32_16x16x32_f16(Aq[kt][0], bw, acc[t4], 0, 0, 0);
          accL[t4] = __builtin_amdgcn_mfma_f32_16x16x32_f16(Aq[kt][1], bw, accL[t4], 0, 0, 0);
        }
      }
      if (!early) {
        pollr(ppf, (unsigned)(s + 1));
#pragma unroll
        for (int kt = 0; kt < 16; ++kt) {
          Ap[kt][0] = *(const f16x8*)(aph + kt * 2048);
          Ap[kt][1] = *(const f16x8*)(apl + kt * 2048);
        }
      }
      // phase 2: p_s @ Wx1
#pragma unroll
      for (int kt = 0; kt < 16; ++kt) {
#pragma unroll
        for (int t4 = 0; t4 < 4; ++t4) {
          f16x8 bw = wx_[(t4 * 16 + kt) * 64 + ln];
          acc[t4]  = __builtin_amdgcn_mfma_f32_16x16x32_f16(Ap[kt][0], bw, acc[t4], 0, 0, 0);
          accL[t4] = __builtin_amdgcn_mfma_f32_16x16x32_f16(Ap[kt][1], bw, accL[t4], 0, 0, 0);
        }
      }
      // ---- epilogue -> wave-private LDS stage ----
      float po[4];
#pragma unroll
      for (int e = 0; e < 4; ++e) {
        po[e] = 0.0f;
#pragma unroll
        for (int nh = 0; nh < 2; ++nh) {
          float v0 = acc[nh*2+0][e] + accL[nh*2+0][e] * LO + b1c0[nh];   // i / f
          float v1 = acc[nh*2+1][e] + accL[nh*2+1][e] * LO + b1c1[nh];   // g / o
          float w0 = __shfl_xor(v0, 8, 16);
          float w1 = __shfl_xor(v1, 8, 16);
          float gi = hiH ? v0 : w0;
          float gf = hiH ? w0 : v0;
          float gg = hiH ? v1 : w1;
          float go = hiH ? w1 : v1;
          float ii = sigm(gi), ff = sigm(gf), tg = tanhx(gg), oo = sigm(go);
          cst[nh][e] = ff * cst[nh][e] + ii * tg;
          float h = oo * tanhx(cst[nh][e]);
          int su = (qd * 4 + e) * 16 + nh * 8 + u;       // wave-local index
          if (hiH) {
            shW[su] = (f16)h;
          } else {
            f16 hh = (f16)h;
            sloW[su] = (f16)((h - (float)hh) * 1024.0f);
          }
          po[e] += hiH ? wfv[nh] * h : 0.0f;
        }
      }
      asm volatile("s_waitcnt lgkmcnt(0)" ::: "memory");
      // ---- wave store: 512B hi + 512B lo, 8B/lane, full-line coverage ----
      {
        size_t boff = (size_t)slot_w * SLOT + (size_t)c * 32768 +
                      (size_t)sl * 1024 + wv * 256;
        st8(q_hi + boff + ln * 4, *(const u64*)(shW + ln * 4));
        st8(q_lo + boff + ln * 4, *(const u64*)(sloW + ln * 4));
      }
      asm volatile("s_waitcnt vmcnt(0)" ::: "memory");   // per-wave drain
      if (ln == 0) stf(QFL(qf, c, sl, wv), (unsigned)(s + 1));
      // deferred head-output reduce + atomic (off the q->q critical path)
#pragma unroll
      for (int e = 0; e < 4; ++e) {
        float r = po[e];
#pragma unroll
        for (int m = 1; m < 16; m <<= 1) r += __shfl_xor(r, m, 16);
        if (cl == 0)
          atomicAdd(part8 + (size_t)(sl & 7) * (NB * NT_) +
                        (size_t)(c * 64 + wv * 16 + qd * 4 + e) * NT_ + s, r);
      }
    }
  }
}

// ---------------------------------------------------------------------------
extern "C" void kernel_launch(void* const* d_in, const int* in_sizes, int n_in,
                              void* d_out, int out_size, void* d_ws, size_t ws_size,
                              hipStream_t stream) {
  (void)in_sizes; (void)n_in; (void)out_size; (void)ws_size;
  const float* inp = (const float*)d_in[0];
  const float* Wx0 = (const float*)d_in[1];
  const float* Wh0 = (const float*)d_in[2];
  const float* b0  = (const float*)d_in[3];
  const float* Wx1 = (const float*)d_in[4];
  const float* Wh1 = (const float*)d_in[5];
  const float* b1  = (const float*)d_in[6];
  const float* Wf  = (const float*)d_in[7];
  const float* bf  = (const float*)d_in[8];

  const size_t MB = 1u << 20;
  const size_t OFF_W    = 0;                 // 6 MiB tiled fp16 weights
  const size_t OFF_XT   = 6 * MB;            // 1 MiB
  const size_t OFF_PHI  = 7 * MB;            // 4 MiB (RING x 256 KB)
  const size_t OFF_PLO  = 11 * MB;
  const size_t OFF_QHI  = 15 * MB;
  const size_t OFF_QLO  = 19 * MB;
  const size_t OFF_PART = 23 * MB;           // 8 MiB
  const size_t OFF_CTR  = 31 * MB;           // flags: pf 64KB + qf 64KB

  char* ws = (char*)d_ws;
  f16* wsl = (f16*)(ws + OFF_W);
  float* xT = (float*)(ws + OFF_XT);
  unsigned short* phi = (unsigned short*)(ws + OFF_PHI);
  unsigned short* plo = (unsigned short*)(ws + OFF_PLO);
  unsigned short* qhi = (unsigned short*)(ws + OFF_QHI);
  unsigned short* qlo = (unsigned short*)(ws + OFF_QLO);
  float* part8 = (float*)(ws + OFF_PART);
  unsigned int* pfl = (unsigned int*)(ws + OFF_CTR);
  unsigned int* qfl = pfl + 16384;           // pf = 512 lines * 32 u32
  float* out = (float*)d_out;

  (void)hipFuncSetAttribute((const void*)lstm_main,
                            hipFuncAttributeMaxDynamicSharedMemorySize, 135168);

  // zero rings + partials + flags (contiguous; flags 128 KB)
  (void)hipMemsetAsync(ws + OFF_PHI, 0, (OFF_CTR + 131072) - OFF_PHI, stream);

  prep_xT<<<1024, 256, 0, stream>>>(inp, xT);
  prep_w<<<12288, 256, 0, stream>>>(Wh0, Wx1, Wh1, wsl);

  lstm_main<<<256, 256, 135168, stream>>>(xT, wsl, Wx0, b0, b1, Wf,
                                          phi, plo, qhi, qlo, pfl, qfl, part8);

  reduce_out<<<1024, 256, 0, stream>>>(part8, bf, out);
}